// Round 1
// baseline (2060.720 us; speedup 1.0000x reference)
//
#include <hip/hip_runtime.h>
#include <cstdint>
#include <cstddef>

#define N_B 128
#define N_I 784
#define N_H 410
#define N_O 10
#define TT  300
#define KL  64
#define NW  25          // ceil(784/32) bitmask words per (n,t)
#define NC  32          // batch chunk
#define NCHUNK (N_B / NC)

// ---- k_pack: Poisson encode, pack spikes as bitmasks over input dim ----
// grid (NW, N_B), block 320 (lane = t, coalesced over rand_u's trailing T dim)
__global__ void k_pack(const float* __restrict__ rand_u, const float* __restrict__ img,
                       uint32_t* __restrict__ s0w) {
  int w = blockIdx.x;
  int n = blockIdx.y;
  int t = threadIdx.x;
  if (t >= TT) return;
  uint32_t bits = 0;
  int ibase = w * 32;
  for (int b = 0; b < 32; ++b) {
    int i = ibase + b;
    uint32_t on = 0;
    if (i < N_I) {
      float r = rand_u[((size_t)n * N_I + i) * TT + t];
      float p = img[(size_t)n * N_I + i];
      on = (r < p) ? 1u : 0u;
    }
    bits |= on << b;
  }
  s0w[((size_t)n * TT + t) * NW + w] = bits;
}

// ---- k_w1t: transpose W1 [410][784] -> [784][410] so lane=o is coalesced ----
__global__ void k_w1t(const float* __restrict__ W1, float* __restrict__ W1T) {
  int i = blockIdx.x;
  int o = threadIdx.x;
  if (o < N_H) W1T[(size_t)i * N_H + o] = W1[(size_t)o * N_I + i];
}

// ---- k_eps: SRM alpha kernel in f64 ----
__global__ void k_eps(double* __restrict__ eps) {
  int k = threadIdx.x;
  if (k < KL) {
    double td = (double)k;
    eps[k] = (td / 10.0) * exp(1.0 - td / 10.0);
  }
}

// ---- k_gemm1: a1[nn][t][o] = sum over set bits of W1T[i][o], f64 accum ----
// grid (TT, NC); block 256; each thread covers o=tid and o=tid+256 (clamped)
__global__ void k_gemm1(const uint32_t* __restrict__ s0w, const float* __restrict__ W1T,
                        double* __restrict__ a1, int n0) {
  int t  = blockIdx.x;
  int nn = blockIdx.y;
  int n  = n0 + nn;
  int o1 = threadIdx.x;
  int o2 = o1 + 256; if (o2 > N_H - 1) o2 = N_H - 1;   // clamp; store guarded
  const uint32_t* wrow = &s0w[((size_t)n * TT + t) * NW];
  double acc1 = 0.0, acc2 = 0.0;
  for (int w = 0; w < NW; ++w) {
    uint32_t m = (uint32_t)__builtin_amdgcn_readfirstlane((int)wrow[w]); // block-uniform -> SGPR
    int ibase = w * 32;
    while (m) {
      int b = __builtin_ctz(m);
      m &= m - 1;
      const float* col = &W1T[(size_t)(ibase + b) * N_H];
      acc1 += (double)col[o1];
      acc2 += (double)col[o2];
    }
  }
  double* arow = &a1[((size_t)nn * TT + t) * N_H];
  arow[o1] = acc1;
  if (o1 + 256 < N_H) arow[o1 + 256] = acc2;
}

// ---- k_fir1: truncated SRM FIR over t (f64) + threshold -> s1 bytes ----
// grid (ceil(TT/8), NC); block 256; thread covers o=tid, tid+256; 8 t-outputs each
__global__ void k_fir1(const double* __restrict__ a1, const double* __restrict__ eps,
                       uint8_t* __restrict__ s1) {
  int t0 = blockIdx.x * 8;
  int nn = blockIdx.y;
  int o1 = threadIdx.x;
  int o2 = o1 + 256; if (o2 > N_H - 1) o2 = N_H - 1;
  double u1[8], u2[8];
  #pragma unroll
  for (int j = 0; j < 8; ++j) { u1[j] = 0.0; u2[j] = 0.0; }
  int slo = t0 - (KL - 1); if (slo < 0) slo = 0;
  int shi = t0 + 7;        if (shi > TT - 1) shi = TT - 1;
  for (int s = slo; s <= shi; ++s) {
    const double* arow = &a1[((size_t)nn * TT + s) * N_H];
    double v1 = arow[o1];
    double v2 = arow[o2];
    int k0 = t0 - s;
    #pragma unroll
    for (int j = 0; j < 8; ++j) {
      int k  = k0 + j;
      int kc = k & 63;                       // always-safe index
      bool ok = (k >= 0) && (k < KL);
      double e = ok ? eps[kc] : 0.0;
      u1[j] += e * v1;
      u2[j] += e * v2;
    }
  }
  #pragma unroll
  for (int j = 0; j < 8; ++j) {
    int t = t0 + j;
    if (t < TT) {
      s1[((size_t)nn * N_H + o1) * TT + t] = (u1[j] >= 10.0) ? 1 : 0;
      if (o1 + 256 < N_H)
        s1[((size_t)nn * N_H + (o1 + 256)) * TT + t] = (u2[j] >= 10.0) ? 1 : 0;
    }
  }
}

// ---- k_gemm2: a2[nn][o][t] = sum_h s1 * W2[o][h], f64 accum ----
__global__ void k_gemm2(const uint8_t* __restrict__ s1, const float* __restrict__ W2,
                        double* __restrict__ a2) {
  __shared__ float w2s[N_O * N_H];
  for (int i = threadIdx.x; i < N_O * N_H; i += 256) w2s[i] = W2[i];
  __syncthreads();
  int flat = blockIdx.x * 256 + threadIdx.x;
  if (flat >= NC * TT) return;
  int t  = flat % TT;
  int nn = flat / TT;
  double acc[N_O];
  #pragma unroll
  for (int o = 0; o < N_O; ++o) acc[o] = 0.0;
  for (int h = 0; h < N_H; ++h) {
    double sv = (double)s1[((size_t)nn * N_H + h) * TT + t];
    #pragma unroll
    for (int o = 0; o < N_O; ++o) acc[o] += sv * (double)w2s[o * N_H + h];
  }
  #pragma unroll
  for (int o = 0; o < N_O; ++o) a2[((size_t)nn * N_O + o) * TT + t] = acc[o];
}

// ---- k_fir2: FIR + threshold -> final spikes (f32 out) ----
__global__ void k_fir2(const double* __restrict__ a2, const double* __restrict__ eps,
                       float* __restrict__ out, int n0) {
  int flat = blockIdx.x * 256 + threadIdx.x;
  if (flat >= NC * N_O * TT) return;
  int t    = flat % TT;
  int rest = flat / TT;
  int o    = rest % N_O;
  int nn   = rest / N_O;
  const double* arow = &a2[((size_t)nn * N_O + o) * TT];
  double u = 0.0;
  int kmax = (t < KL - 1) ? t : (KL - 1);
  for (int k = 0; k <= kmax; ++k) u += eps[k] * arow[t - k];
  out[(((size_t)(n0 + nn) * N_O) + o) * TT + t] = (u >= 10.0) ? 1.0f : 0.0f;
}

extern "C" void kernel_launch(void* const* d_in, const int* in_sizes, int n_in,
                              void* d_out, int out_size, void* d_ws, size_t ws_size,
                              hipStream_t stream) {
  const float* img   = (const float*)d_in[0];
  const float* randu = (const float*)d_in[1];
  const float* W1    = (const float*)d_in[2];
  const float* W2    = (const float*)d_in[3];
  float* out = (float*)d_out;

  char* ws = (char*)d_ws;
  size_t off = 0;
  auto alloc = [&](size_t bytes) -> void* {
    void* p = ws + off;
    off = (off + bytes + 511) & ~(size_t)511;
    return p;
  };
  uint32_t* s0w  = (uint32_t*)alloc((size_t)N_B * TT * NW * sizeof(uint32_t)); // 3.84 MB
  float*    W1T  = (float*)   alloc((size_t)N_I * N_H * sizeof(float));        // 1.29 MB
  double*   epsb = (double*)  alloc((size_t)KL * sizeof(double));
  double*   a1   = (double*)  alloc((size_t)NC * TT * N_H * sizeof(double));   // 31.5 MB
  uint8_t*  s1   = (uint8_t*) alloc((size_t)NC * N_H * TT);                    // 3.94 MB
  double*   a2   = (double*)  alloc((size_t)NC * N_O * TT * sizeof(double));   // 0.77 MB
  if (off > ws_size) return;  // workspace too small -> fail loudly

  k_pack<<<dim3(NW, N_B), 320, 0, stream>>>(randu, img, s0w);
  k_w1t <<<dim3(N_I),     512, 0, stream>>>(W1, W1T);
  k_eps <<<dim3(1),        64, 0, stream>>>(epsb);

  for (int c = 0; c < NCHUNK; ++c) {
    int n0 = c * NC;
    k_gemm1<<<dim3(TT, NC),                          256, 0, stream>>>(s0w, W1T, a1, n0);
    k_fir1 <<<dim3((TT + 7) / 8, NC),                256, 0, stream>>>(a1, epsb, s1);
    k_gemm2<<<dim3((NC * TT + 255) / 256),           256, 0, stream>>>(s1, W2, a2);
    k_fir2 <<<dim3((NC * N_O * TT + 255) / 256),     256, 0, stream>>>(a2, epsb, out, n0);
  }
}

// Round 2
// 872.452 us; speedup vs baseline: 2.3620x; 2.3620x over previous
//
#include <hip/hip_runtime.h>
#include <cstdint>
#include <cstddef>

#define N_B 128
#define N_I 784
#define N_H 410
#define N_O 10
#define TT  300
#define KL  64
#define NW  26          // 832 bits = padded K words per (n,t)
#define KP  832         // K padded to 13*64
#define NKS 13          // K-steps of 64
#define NTILES 26       // N-tiles of 16 (410 -> 416)
#define NHP 416         // padded hidden width for a1 rows
#define NDIG 4          // base-256 digits of round(W1 * 2^28)
#define NC  32          // batch chunk
#define NCHUNK (N_B / NC)
#define ASTRIDE 848     // LDS A row stride in bytes (832 + 16)

typedef int v4i __attribute__((ext_vector_type(4)));

__device__ __forceinline__ uint32_t expand4(uint32_t v) {
  // 4 bits -> 4 bytes (0/1): collision-free magic multiply
  return (v * 0x00204081u) & 0x01010101u;
}

// ---- k_pack: Poisson encode -> bitmask words (bit i = spike), K-padded ----
__global__ void k_pack(const float* __restrict__ rand_u, const float* __restrict__ img,
                       uint32_t* __restrict__ s0w) {
  int w = blockIdx.x;
  int n = blockIdx.y;
  int t = threadIdx.x;
  if (t >= TT) return;
  uint32_t bits = 0;
  int ibase = w * 32;
  for (int b = 0; b < 32; ++b) {
    int i = ibase + b;
    uint32_t on = 0;
    if (i < N_I) {
      float r = rand_u[((size_t)n * N_I + i) * TT + t];
      float p = img[(size_t)n * N_I + i];
      on = (r < p) ? 1u : 0u;
    }
    bits |= on << b;
  }
  s0w[((size_t)n * TT + t) * NW + w] = bits;
}

// ---- k_eps: SRM alpha kernel, raw [0..63] and 2^-28-scaled [64..127] ----
__global__ void k_eps(double* __restrict__ epsb) {
  int k = threadIdx.x;
  if (k < KL) {
    double td = (double)k;
    double e = (td / 10.0) * exp(1.0 - td / 10.0);
    epsb[k] = e;
    epsb[KL + k] = e * (1.0 / 268435456.0);
  }
}

// ---- k_bprep: W1 -> 4 signed-i8 digit matrices in MFMA fragment-major layout ----
// Bf[((d*NTILES+nt)*NKS+ks)*64 + lane] = 16 bytes: B[k=ks*64+(lane>>4)*16+j][n=nt*16+(lane&15)]
__global__ void k_bprep(const float* __restrict__ W1, v4i* __restrict__ Bf) {
  int bid  = blockIdx.x;              // ((d*NTILES + nt)*NKS + ks)
  int lane = threadIdx.x;
  int ks   = bid % NKS;
  int rest = bid / NKS;
  int nt   = rest % NTILES;
  int d    = rest / NTILES;
  int o     = nt * 16 + (lane & 15);
  int kbase = ks * 64 + (lane >> 4) * 16;
  uint32_t wds[4] = {0, 0, 0, 0};
  for (int j = 0; j < 16; ++j) {
    int k = kbase + j;
    int dig = 0;
    if (o < N_H && k < N_I) {
      double w = (double)W1[(size_t)o * N_I + k];
      int r = (int)llround(w * 268435456.0);   // |r| <= ~6*2^28 < 2^31
      for (int dd = 0; dd <= d; ++dd) {        // balanced base-256 digits
        dig = (int)(int8_t)(uint8_t)(r & 255);
        r = (r - dig) >> 8;
      }
    }
    wds[j >> 2] |= ((uint32_t)(uint8_t)(int8_t)dig) << (8 * (j & 3));
  }
  v4i v; v[0] = (int)wds[0]; v[1] = (int)wds[1]; v[2] = (int)wds[2]; v[3] = (int)wds[3];
  Bf[(size_t)bid * 64 + lane] = v;
}

// ---- k_gemm1m: exact int8-digit MFMA GEMM; a1 = integer-valued f64 (units 2^-28) ----
// grid (rows/64, 7); block 256 (4 waves). Wave handles 4 M-tiles x 1 N-tile x 4 digits.
__global__ __launch_bounds__(256, 2) void k_gemm1m(const uint32_t* __restrict__ s0w,
                                                   const v4i* __restrict__ Bf,
                                                   double* __restrict__ a1, int rowbase) {
  __shared__ __attribute__((aligned(16))) uint8_t Alds[64 * ASTRIDE];
  int tid = threadIdx.x;
  int mb = blockIdx.x, nb = blockIdx.y;
  // Stage A: expand 64 rows x 26 mask words -> 64 x 832 i8 in LDS (full K, once)
  const uint32_t* wbase = s0w + (size_t)(rowbase + mb * 64) * NW;
  for (int idx = tid; idx < 64 * NW; idx += 256) {
    int row = idx / NW;
    int w = idx - row * NW;
    uint32_t bits = wbase[idx];
    uint4 q0, q1;
    q0.x = expand4(bits & 0xF);         q0.y = expand4((bits >> 4) & 0xF);
    q0.z = expand4((bits >> 8) & 0xF);  q0.w = expand4((bits >> 12) & 0xF);
    q1.x = expand4((bits >> 16) & 0xF); q1.y = expand4((bits >> 20) & 0xF);
    q1.z = expand4((bits >> 24) & 0xF); q1.w = expand4((bits >> 28) & 0xF);
    uint8_t* dst = &Alds[(size_t)row * ASTRIDE + w * 32];
    *(uint4*)dst = q0;
    *(uint4*)(dst + 16) = q1;
  }
  __syncthreads();
  int wave = tid >> 6, lane = tid & 63;
  int nt = nb * 4 + wave;
  if (nt >= NTILES) return;            // after the only barrier: safe
  int lrow = lane & 15, quad = lane >> 4;
  const v4i* bb = Bf + (size_t)nt * NKS * 64 + lane;
  const size_t dstr = (size_t)NTILES * NKS * 64;
  v4i acc[4][NDIG];
  #pragma unroll
  for (int mt = 0; mt < 4; ++mt)
    #pragma unroll
    for (int d = 0; d < NDIG; ++d) { acc[mt][d][0]=0; acc[mt][d][1]=0; acc[mt][d][2]=0; acc[mt][d][3]=0; }
  uint32_t abase[4];
  #pragma unroll
  for (int mt = 0; mt < 4; ++mt) abase[mt] = (uint32_t)((mt * 16 + lrow) * ASTRIDE + quad * 16);
  for (int ks = 0; ks < NKS; ++ks) {
    v4i af[4];
    #pragma unroll
    for (int mt = 0; mt < 4; ++mt) af[mt] = *(const v4i*)&Alds[abase[mt] + ks * 64];
    v4i bf[NDIG];
    #pragma unroll
    for (int d = 0; d < NDIG; ++d) bf[d] = bb[(size_t)d * dstr + ks * 64];
    #pragma unroll
    for (int mt = 0; mt < 4; ++mt)
      #pragma unroll
      for (int d = 0; d < NDIG; ++d)
        acc[mt][d] = __builtin_amdgcn_mfma_i32_16x16x64_i8(af[mt], bf[d], acc[mt][d], 0, 0, 0);
  }
  int o = nt * 16 + lrow;               // C/D: col = lane&15
  if (o < N_H) {
    #pragma unroll
    for (int mt = 0; mt < 4; ++mt)
      #pragma unroll
      for (int r = 0; r < 4; ++r) {     // C/D: row = (lane>>4)*4 + reg
        int m = mb * 64 + mt * 16 + quad * 4 + r;
        double v = (double)acc[mt][0][r]
                 + 256.0       * (double)acc[mt][1][r]
                 + 65536.0     * (double)acc[mt][2][r]
                 + 16777216.0  * (double)acc[mt][3][r];   // exact integer < 2^53
        a1[(size_t)m * NHP + o] = v;
      }
  }
}

// ---- k_fir1: f64 FIR (scaled eps) + threshold -> s1; 16 t-outputs per thread ----
__global__ void k_fir1(const double* __restrict__ a1, const double* __restrict__ epsb,
                       uint8_t* __restrict__ s1) {
  __shared__ double epsl[KL];
  if (threadIdx.x < KL) epsl[threadIdx.x] = epsb[KL + threadIdx.x];  // scaled by 2^-28
  __syncthreads();
  int t0 = blockIdx.x * 16;
  int nn = blockIdx.y;
  int o1 = threadIdx.x;
  int o2 = o1 + 256; if (o2 > N_H - 1) o2 = N_H - 1;
  double u1[16], u2[16];
  #pragma unroll
  for (int j = 0; j < 16; ++j) { u1[j] = 0.0; u2[j] = 0.0; }
  int slo = t0 - (KL - 1); if (slo < 0) slo = 0;
  int shi = t0 + 15;       if (shi > TT - 1) shi = TT - 1;
  for (int s = slo; s <= shi; ++s) {
    const double* arow = &a1[((size_t)nn * TT + s) * NHP];
    double v1 = arow[o1];
    double v2 = arow[o2];
    int k0 = t0 - s;
    #pragma unroll
    for (int j = 0; j < 16; ++j) {
      int k = k0 + j;
      bool ok = (k >= 0) && (k < KL);
      double e = ok ? epsl[k & 63] : 0.0;
      u1[j] += e * v1;
      u2[j] += e * v2;
    }
  }
  #pragma unroll
  for (int j = 0; j < 16; ++j) {
    int t = t0 + j;
    if (t < TT) {
      s1[((size_t)nn * N_H + o1) * TT + t] = (u1[j] >= 10.0) ? 1 : 0;
      if (o1 + 256 < N_H)
        s1[((size_t)nn * N_H + (o1 + 256)) * TT + t] = (u2[j] >= 10.0) ? 1 : 0;
    }
  }
}

// ---- k_gemm2: a2[nn][o][t] = sum_h s1 * W2[o][h], f64 (exact) ----
__global__ void k_gemm2(const uint8_t* __restrict__ s1, const float* __restrict__ W2,
                        double* __restrict__ a2) {
  __shared__ float w2s[N_O * N_H];
  for (int i = threadIdx.x; i < N_O * N_H; i += 256) w2s[i] = W2[i];
  __syncthreads();
  int flat = blockIdx.x * 256 + threadIdx.x;
  if (flat >= NC * TT) return;
  int t  = flat % TT;
  int nn = flat / TT;
  double acc[N_O];
  #pragma unroll
  for (int o = 0; o < N_O; ++o) acc[o] = 0.0;
  for (int h = 0; h < N_H; ++h) {
    double sv = (double)s1[((size_t)nn * N_H + h) * TT + t];
    #pragma unroll
    for (int o = 0; o < N_O; ++o) acc[o] += sv * (double)w2s[o * N_H + h];
  }
  #pragma unroll
  for (int o = 0; o < N_O; ++o) a2[((size_t)nn * N_O + o) * TT + t] = acc[o];
}

// ---- k_fir2: FIR (raw eps) + threshold -> final spikes (f32) ----
__global__ void k_fir2(const double* __restrict__ a2, const double* __restrict__ epsb,
                       float* __restrict__ out, int n0) {
  int flat = blockIdx.x * 256 + threadIdx.x;
  if (flat >= NC * N_O * TT) return;
  int t    = flat % TT;
  int rest = flat / TT;
  int o    = rest % N_O;
  int nn   = rest / N_O;
  const double* arow = &a2[((size_t)nn * N_O + o) * TT];
  double u = 0.0;
  int kmax = (t < KL - 1) ? t : (KL - 1);
  for (int k = 0; k <= kmax; ++k) u += epsb[k] * arow[t - k];
  out[(((size_t)(n0 + nn) * N_O) + o) * TT + t] = (u >= 10.0) ? 1.0f : 0.0f;
}

extern "C" void kernel_launch(void* const* d_in, const int* in_sizes, int n_in,
                              void* d_out, int out_size, void* d_ws, size_t ws_size,
                              hipStream_t stream) {
  const float* img   = (const float*)d_in[0];
  const float* randu = (const float*)d_in[1];
  const float* W1    = (const float*)d_in[2];
  const float* W2    = (const float*)d_in[3];
  float* out = (float*)d_out;

  char* ws = (char*)d_ws;
  size_t off = 0;
  auto alloc = [&](size_t bytes) -> void* {
    void* p = ws + off;
    off = (off + bytes + 511) & ~(size_t)511;
    return p;
  };
  uint32_t* s0w  = (uint32_t*)alloc((size_t)N_B * TT * NW * sizeof(uint32_t));   // 4.0 MB
  v4i*      Bf   = (v4i*)     alloc((size_t)NDIG * NTILES * NKS * 64 * 16);      // 1.4 MB
  double*   epsb = (double*)  alloc((size_t)2 * KL * sizeof(double));
  double*   a1   = (double*)  alloc((size_t)NC * TT * NHP * sizeof(double));     // 32.0 MB
  uint8_t*  s1   = (uint8_t*) alloc((size_t)NC * N_H * TT);                      // 3.9 MB
  double*   a2   = (double*)  alloc((size_t)NC * N_O * TT * sizeof(double));     // 0.8 MB
  if (off > ws_size) return;

  k_pack <<<dim3(NW, N_B), 320, 0, stream>>>(randu, img, s0w);
  k_eps  <<<dim3(1), 64, 0, stream>>>(epsb);
  k_bprep<<<dim3(NDIG * NTILES * NKS), 64, 0, stream>>>(W1, Bf);

  for (int c = 0; c < NCHUNK; ++c) {
    int n0 = c * NC;
    k_gemm1m<<<dim3(NC * TT / 64, 7),            256, 0, stream>>>(s0w, Bf, a1, n0 * TT);
    k_fir1  <<<dim3((TT + 15) / 16, NC),         256, 0, stream>>>(a1, epsb, s1);
    k_gemm2 <<<dim3((NC * TT + 255) / 256),      256, 0, stream>>>(s1, W2, a2);
    k_fir2  <<<dim3((NC * N_O * TT + 255) / 256),256, 0, stream>>>(a2, epsb, out, n0);
  }
}

// Round 4
// 402.996 us; speedup vs baseline: 5.1135x; 2.1649x over previous
//
#include <hip/hip_runtime.h>
#include <cstdint>
#include <cstddef>

#define N_B 128
#define N_I 784
#define N_H 410
#define N_O 10
#define TT  300
#define KL  64
#define NW  26          // bitmask words per (n,t) (832 bits, K-padded)
#define NKS 13          // layer-1 K-steps of 64 (832)
#define NTILES 26       // layer-1 N-tiles of 16 (410 -> 416)
#define NHP 416         // padded hidden width (a1 row length)
#define SSTR 448        // s1 row stride (7*64, layer-2 K-padded)
#define NKS2 7          // layer-2 K-steps of 64 (448)
#define NDIG 4          // base-256 digits of round(W * 2^28)
#define ASTRIDE 848     // gemm1m LDS A row stride bytes

typedef int v4i __attribute__((ext_vector_type(4)));

__device__ __forceinline__ uint32_t expand4(uint32_t v) {
  return (v * 0x00204081u) & 0x01010101u;   // 4 bits -> 4 bytes (0/1)
}

// ---- k_pack: thread owns (n,t), all 26 words; 32-unrolled loads for ILP ----
__global__ void k_pack(const float* __restrict__ rand_u, const float* __restrict__ img,
                       uint32_t* __restrict__ s0w) {
  int n = blockIdx.y;
  int t = blockIdx.x * 64 + threadIdx.x;
  if (t >= TT) return;
  const float* rb = rand_u + (size_t)n * N_I * TT + t;
  const float* ib = img + (size_t)n * N_I;
  uint32_t* dst = s0w + ((size_t)n * TT + t) * NW;
  #pragma unroll 1
  for (int w = 0; w < 25; ++w) {
    int ib32 = w * 32;
    float r[32];
    #pragma unroll
    for (int b = 0; b < 32; ++b) {
      int i = ib32 + b;
      r[b] = (i < N_I) ? rb[(size_t)i * TT] : 2.0f;   // 2.0 > any p -> no spike
    }
    uint32_t bits = 0;
    #pragma unroll
    for (int b = 0; b < 32; ++b) {
      int i = ib32 + b;
      float p = (i < N_I) ? ib[i] : 0.0f;             // uniform -> scalar load
      bits |= (r[b] < p ? 1u : 0u) << b;
    }
    dst[w] = bits;
  }
  dst[25] = 0;
}

// ---- k_eps: raw eps [0..63]; 2^-28-scaled eps [64..127] (round-2 layout) ----
__global__ void k_eps(double* __restrict__ epsb) {
  int k = threadIdx.x;
  if (k < KL) {
    double td = (double)k;
    double e = (td / 10.0) * exp(1.0 - td / 10.0);
    epsb[k] = e;
    epsb[KL + k] = e * (1.0 / 268435456.0);
  }
}

// ---- k_bprep: W1 -> 4 signed-i8 digit matrices, MFMA fragment-major ----
__global__ void k_bprep(const float* __restrict__ W1, v4i* __restrict__ Bf) {
  int bid  = blockIdx.x;              // ((d*NTILES + nt)*NKS + ks)
  int lane = threadIdx.x;
  int ks   = bid % NKS;
  int rest = bid / NKS;
  int nt   = rest % NTILES;
  int d    = rest / NTILES;
  int o     = nt * 16 + (lane & 15);
  int kbase = ks * 64 + (lane >> 4) * 16;
  uint32_t wds[4] = {0, 0, 0, 0};
  for (int j = 0; j < 16; ++j) {
    int k = kbase + j;
    int dig = 0;
    if (o < N_H && k < N_I) {
      double w = (double)W1[(size_t)o * N_I + k];
      int r = (int)llround(w * 268435456.0);
      for (int dd = 0; dd <= d; ++dd) {
        dig = (int)(int8_t)(uint8_t)(r & 255);
        r = (r - dig) >> 8;
      }
    }
    wds[j >> 2] |= ((uint32_t)(uint8_t)(int8_t)dig) << (8 * (j & 3));
  }
  v4i v; v[0] = (int)wds[0]; v[1] = (int)wds[1]; v[2] = (int)wds[2]; v[3] = (int)wds[3];
  Bf[(size_t)bid * 64 + lane] = v;
}

// ---- k_bprep2: W2 -> 4 signed-i8 digit matrices, fragment-major ----
__global__ void k_bprep2(const float* __restrict__ W2, v4i* __restrict__ Bf2) {
  int bid  = blockIdx.x;              // d*NKS2 + ks
  int lane = threadIdx.x;
  int ks = bid % NKS2, d = bid / NKS2;
  int o     = lane & 15;
  int kbase = ks * 64 + (lane >> 4) * 16;
  uint32_t wds[4] = {0, 0, 0, 0};
  for (int j = 0; j < 16; ++j) {
    int k = kbase + j;
    int dig = 0;
    if (o < N_O && k < N_H) {
      double w = (double)W2[(size_t)o * N_H + k];
      int r = (int)llround(w * 268435456.0);
      for (int dd = 0; dd <= d; ++dd) {
        dig = (int)(int8_t)(uint8_t)(r & 255);
        r = (r - dig) >> 8;
      }
    }
    wds[j >> 2] |= ((uint32_t)(uint8_t)(int8_t)dig) << (8 * (j & 3));
  }
  v4i v; v[0] = (int)wds[0]; v[1] = (int)wds[1]; v[2] = (int)wds[2]; v[3] = (int)wds[3];
  Bf2[(size_t)bid * 64 + lane] = v;
}

// ---- k_gemm1m: exact int8-digit MFMA; a1 = integer-valued f64 (units 2^-28) ----
__global__ __launch_bounds__(256, 2) void k_gemm1m(const uint32_t* __restrict__ s0w,
                                                   const v4i* __restrict__ Bf,
                                                   double* __restrict__ a1, int rowbase) {
  __shared__ __attribute__((aligned(16))) uint8_t Alds[64 * ASTRIDE];
  int tid = threadIdx.x;
  int mb = blockIdx.x, nb = blockIdx.y;
  const uint32_t* wbase = s0w + (size_t)(rowbase + mb * 64) * NW;
  for (int idx = tid; idx < 64 * NW; idx += 256) {
    int row = idx / NW;
    int w = idx - row * NW;
    uint32_t bits = wbase[idx];
    uint4 q0, q1;
    q0.x = expand4(bits & 0xF);         q0.y = expand4((bits >> 4) & 0xF);
    q0.z = expand4((bits >> 8) & 0xF);  q0.w = expand4((bits >> 12) & 0xF);
    q1.x = expand4((bits >> 16) & 0xF); q1.y = expand4((bits >> 20) & 0xF);
    q1.z = expand4((bits >> 24) & 0xF); q1.w = expand4((bits >> 28) & 0xF);
    uint8_t* dst = &Alds[(size_t)row * ASTRIDE + w * 32];
    *(uint4*)dst = q0;
    *(uint4*)(dst + 16) = q1;
  }
  __syncthreads();
  int wave = tid >> 6, lane = tid & 63;
  int nt = nb * 4 + wave;
  if (nt >= NTILES) return;
  int lrow = lane & 15, quad = lane >> 4;
  const v4i* bb = Bf + (size_t)nt * NKS * 64 + lane;
  const size_t dstr = (size_t)NTILES * NKS * 64;
  v4i acc[4][NDIG];
  #pragma unroll
  for (int mt = 0; mt < 4; ++mt)
    #pragma unroll
    for (int d = 0; d < NDIG; ++d) { acc[mt][d][0]=0; acc[mt][d][1]=0; acc[mt][d][2]=0; acc[mt][d][3]=0; }
  uint32_t abase[4];
  #pragma unroll
  for (int mt = 0; mt < 4; ++mt) abase[mt] = (uint32_t)((mt * 16 + lrow) * ASTRIDE + quad * 16);
  for (int ks = 0; ks < NKS; ++ks) {
    v4i af[4];
    #pragma unroll
    for (int mt = 0; mt < 4; ++mt) af[mt] = *(const v4i*)&Alds[abase[mt] + ks * 64];
    v4i bf[NDIG];
    #pragma unroll
    for (int d = 0; d < NDIG; ++d) bf[d] = bb[(size_t)d * dstr + ks * 64];
    #pragma unroll
    for (int mt = 0; mt < 4; ++mt)
      #pragma unroll
      for (int d = 0; d < NDIG; ++d)
        acc[mt][d] = __builtin_amdgcn_mfma_i32_16x16x64_i8(af[mt], bf[d], acc[mt][d], 0, 0, 0);
  }
  int o = nt * 16 + lrow;               // pad cols o in [410,416) get exact zeros
  #pragma unroll
  for (int mt = 0; mt < 4; ++mt)
    #pragma unroll
    for (int r = 0; r < 4; ++r) {
      int m = mb * 64 + mt * 16 + quad * 4 + r;
      double v = (double)acc[mt][0][r]
               + 256.0      * (double)acc[mt][1][r]
               + 65536.0    * (double)acc[mt][2][r]
               + 16777216.0 * (double)acc[mt][3][r];
      a1[(size_t)m * NHP + o] = v;
    }
}

// ---- k_fir1: round-2 VERIFIED scalar f64 FIR; only the s1 store layout changed ----
__global__ void k_fir1(const double* __restrict__ a1, const double* __restrict__ epsb,
                       uint8_t* __restrict__ s1) {
  __shared__ double epsl[KL];
  if (threadIdx.x < KL) epsl[threadIdx.x] = epsb[KL + threadIdx.x];  // scaled by 2^-28
  __syncthreads();
  int t0 = blockIdx.x * 16;
  int nn = blockIdx.y;
  int o1 = threadIdx.x;
  int o2 = o1 + 256; if (o2 > N_H - 1) o2 = N_H - 1;
  double u1[16], u2[16];
  #pragma unroll
  for (int j = 0; j < 16; ++j) { u1[j] = 0.0; u2[j] = 0.0; }
  int slo = t0 - (KL - 1); if (slo < 0) slo = 0;
  int shi = t0 + 15;       if (shi > TT - 1) shi = TT - 1;
  for (int s = slo; s <= shi; ++s) {
    const double* arow = &a1[((size_t)nn * TT + s) * NHP];
    double v1 = arow[o1];
    double v2 = arow[o2];
    int k0 = t0 - s;
    #pragma unroll
    for (int j = 0; j < 16; ++j) {
      int k = k0 + j;
      bool ok = (k >= 0) && (k < KL);
      double e = ok ? epsl[k & 63] : 0.0;
      u1[j] += e * v1;
      u2[j] += e * v2;
    }
  }
  #pragma unroll
  for (int j = 0; j < 16; ++j) {
    int t = t0 + j;
    if (t < TT) {
      s1[((size_t)nn * TT + t) * SSTR + o1] = (u1[j] >= 10.0) ? 1 : 0;
      if (o1 + 256 < N_H)
        s1[((size_t)nn * TT + t) * SSTR + (o1 + 256)] = (u2[j] >= 10.0) ? 1 : 0;
    }
  }
}

// ---- k_gemm2m: layer-2 exact int8-digit MFMA; a2 integer-valued f64 (x 2^28) ----
__global__ void k_gemm2m(const uint8_t* __restrict__ s1, const v4i* __restrict__ Bf2,
                         double* __restrict__ a2) {
  int tid = threadIdx.x;
  int wave = tid >> 6, lane = tid & 63;
  int m0 = (blockIdx.x * 4 + wave) * 16;
  int lrow = lane & 15, quad = lane >> 4;
  v4i acc[NDIG];
  #pragma unroll
  for (int d = 0; d < NDIG; ++d) { acc[d][0]=0; acc[d][1]=0; acc[d][2]=0; acc[d][3]=0; }
  const uint8_t* arow = s1 + (size_t)(m0 + lrow) * SSTR + quad * 16;
  for (int ks = 0; ks < NKS2; ++ks) {
    v4i af = *(const v4i*)(arow + ks * 64);
    #pragma unroll
    for (int d = 0; d < NDIG; ++d) {
      v4i bf = Bf2[(size_t)(d * NKS2 + ks) * 64 + lane];
      acc[d] = __builtin_amdgcn_mfma_i32_16x16x64_i8(af, bf, acc[d], 0, 0, 0);
    }
  }
  int o = lrow;
  if (o < N_O) {
    #pragma unroll
    for (int r = 0; r < 4; ++r) {
      int m = m0 + quad * 4 + r;
      int nn = m / TT;
      int t = m - nn * TT;
      double v = (double)acc[0][r]
               + 256.0      * (double)acc[1][r]
               + 65536.0    * (double)acc[2][r]
               + 16777216.0 * (double)acc[3][r];
      a2[((size_t)nn * N_O + o) * TT + t] = v;
    }
  }
}

// ---- k_fir2: f64 FIR (scaled eps) + threshold -> final spikes ----
__global__ void k_fir2(const double* __restrict__ a2, const double* __restrict__ epsb,
                       float* __restrict__ out, int n0, int nc) {
  int flat = blockIdx.x * 256 + threadIdx.x;
  if (flat >= nc * N_O * TT) return;
  int t    = flat % TT;
  int rest = flat / TT;
  int o    = rest % N_O;
  int nn   = rest / N_O;
  const double* arow = a2 + ((size_t)nn * N_O + o) * TT;
  const double* epsS = epsb + KL;     // scaled eps[k] at 64+k
  double u = 0.0;
  int kmax = (t < KL - 1) ? t : (KL - 1);
  for (int k = 0; k <= kmax; ++k) u += epsS[k] * arow[t - k];
  out[(((size_t)(n0 + nn)) * N_O + o) * TT + t] = (u >= 10.0) ? 1.0f : 0.0f;
}

extern "C" void kernel_launch(void* const* d_in, const int* in_sizes, int n_in,
                              void* d_out, int out_size, void* d_ws, size_t ws_size,
                              hipStream_t stream) {
  const float* img   = (const float*)d_in[0];
  const float* randu = (const float*)d_in[1];
  const float* W1    = (const float*)d_in[2];
  const float* W2    = (const float*)d_in[3];
  float* out = (float*)d_out;

  const size_t fixedB = (((size_t)N_B * TT * NW * 4 + 511) & ~511UL)
                      + (((size_t)NDIG * NTILES * NKS * 64 * 16 + 511) & ~511UL)
                      + (((size_t)NDIG * NKS2 * 64 * 16 + 511) & ~511UL)
                      + ((128 * 8 + 511) & ~511UL);
  const size_t perN = (size_t)TT * NHP * 8 + (size_t)TT * SSTR + (size_t)N_O * TT * 8;
  int nc = 16;
  const int cands[3] = {128, 64, 32};
  for (int ci = 0; ci < 3; ++ci)
    if (fixedB + (size_t)cands[ci] * perN + 8192 <= ws_size) { nc = cands[ci]; break; }
  const int nchunk = N_B / nc;

  char* ws = (char*)d_ws;
  size_t off = 0;
  auto alloc = [&](size_t bytes) -> void* {
    void* p = ws + off;
    off = (off + bytes + 511) & ~(size_t)511;
    return p;
  };
  uint32_t* s0w  = (uint32_t*)alloc((size_t)N_B * TT * NW * sizeof(uint32_t));
  v4i*      Bf   = (v4i*)     alloc((size_t)NDIG * NTILES * NKS * 64 * 16);
  v4i*      Bf2  = (v4i*)     alloc((size_t)NDIG * NKS2 * 64 * 16);
  double*   epsb = (double*)  alloc(128 * sizeof(double));
  double*   a1   = (double*)  alloc((size_t)nc * TT * NHP * sizeof(double));
  uint8_t*  s1   = (uint8_t*) alloc((size_t)nc * TT * SSTR);
  double*   a2   = (double*)  alloc((size_t)nc * N_O * TT * sizeof(double));
  if (off > ws_size) return;

  k_pack  <<<dim3(5, N_B), 64, 0, stream>>>(randu, img, s0w);
  k_eps   <<<dim3(1), 64, 0, stream>>>(epsb);
  k_bprep <<<dim3(NDIG * NTILES * NKS), 64, 0, stream>>>(W1, Bf);
  k_bprep2<<<dim3(NDIG * NKS2), 64, 0, stream>>>(W2, Bf2);

  for (int c = 0; c < nchunk; ++c) {
    int n0 = c * nc;
    k_gemm1m<<<dim3(nc * TT / 64, 7),             256, 0, stream>>>(s0w, Bf, a1, n0 * TT);
    k_fir1  <<<dim3((TT + 15) / 16, nc),          256, 0, stream>>>(a1, epsb, s1);
    k_gemm2m<<<dim3(nc * TT / 64),                256, 0, stream>>>(s1, Bf2, a2);
    k_fir2  <<<dim3((nc * N_O * TT + 255) / 256), 256, 0, stream>>>(a2, epsb, out, n0, nc);
  }
}

// Round 5
// 358.902 us; speedup vs baseline: 5.7417x; 1.1229x over previous
//
#include <hip/hip_runtime.h>
#include <cstdint>
#include <cstddef>

#define N_B 128
#define N_I 784
#define N_H 410
#define N_O 10
#define TT  300
#define KL  64
#define NW  26          // bitmask words per (n,t) (832 bits, K-padded)
#define NKS 13          // layer-1 K-steps of 64 (832)
#define NTILES 26       // layer-1 N-tiles of 16 (410 -> 416)
#define NHP 416         // padded hidden width (a1 row length)
#define SSTR 448        // s1 row stride (7*64, layer-2 K-padded)
#define NKS2 7          // layer-2 K-steps of 64 (448)
#define NDIG 4          // base-256 digits of round(W * 2^28)
#define ASTRIDE 848     // gemm1m LDS A row stride bytes

typedef int v4i __attribute__((ext_vector_type(4)));

__device__ __forceinline__ uint32_t expand4(uint32_t v) {
  return (v * 0x00204081u) & 0x01010101u;   // 4 bits -> 4 bytes (0/1)
}

// ---- k_pack: thread owns (n,t), all 26 words; 32-unrolled loads for ILP ----
__global__ void k_pack(const float* __restrict__ rand_u, const float* __restrict__ img,
                       uint32_t* __restrict__ s0w) {
  int n = blockIdx.y;
  int t = blockIdx.x * 64 + threadIdx.x;
  if (t >= TT) return;
  const float* rb = rand_u + (size_t)n * N_I * TT + t;
  const float* ib = img + (size_t)n * N_I;
  uint32_t* dst = s0w + ((size_t)n * TT + t) * NW;
  #pragma unroll 1
  for (int w = 0; w < 25; ++w) {
    int ib32 = w * 32;
    float r[32];
    #pragma unroll
    for (int b = 0; b < 32; ++b) {
      int i = ib32 + b;
      r[b] = (i < N_I) ? rb[(size_t)i * TT] : 2.0f;   // 2.0 > any p -> no spike
    }
    uint32_t bits = 0;
    #pragma unroll
    for (int b = 0; b < 32; ++b) {
      int i = ib32 + b;
      float p = (i < N_I) ? ib[i] : 0.0f;             // uniform -> scalar load
      bits |= (r[b] < p ? 1u : 0u) << b;
    }
    dst[w] = bits;
  }
  dst[25] = 0;
}

// ---- k_eps: raw eps [0..63]; 2^-28-scaled eps [64..127] ----
__global__ void k_eps(double* __restrict__ epsb) {
  int k = threadIdx.x;
  if (k < KL) {
    double td = (double)k;
    double e = (td / 10.0) * exp(1.0 - td / 10.0);
    epsb[k] = e;
    epsb[KL + k] = e * (1.0 / 268435456.0);
  }
}

// ---- k_bprep: W1 -> 4 signed-i8 digit matrices, MFMA fragment-major ----
__global__ void k_bprep(const float* __restrict__ W1, v4i* __restrict__ Bf) {
  int bid  = blockIdx.x;              // ((d*NTILES + nt)*NKS + ks)
  int lane = threadIdx.x;
  int ks   = bid % NKS;
  int rest = bid / NKS;
  int nt   = rest % NTILES;
  int d    = rest / NTILES;
  int o     = nt * 16 + (lane & 15);
  int kbase = ks * 64 + (lane >> 4) * 16;
  uint32_t wds[4] = {0, 0, 0, 0};
  for (int j = 0; j < 16; ++j) {
    int k = kbase + j;
    int dig = 0;
    if (o < N_H && k < N_I) {
      double w = (double)W1[(size_t)o * N_I + k];
      int r = (int)llround(w * 268435456.0);
      for (int dd = 0; dd <= d; ++dd) {
        dig = (int)(int8_t)(uint8_t)(r & 255);
        r = (r - dig) >> 8;
      }
    }
    wds[j >> 2] |= ((uint32_t)(uint8_t)(int8_t)dig) << (8 * (j & 3));
  }
  v4i v; v[0] = (int)wds[0]; v[1] = (int)wds[1]; v[2] = (int)wds[2]; v[3] = (int)wds[3];
  Bf[(size_t)bid * 64 + lane] = v;
}

// ---- k_bprep2: W2 -> 4 signed-i8 digit matrices, fragment-major ----
__global__ void k_bprep2(const float* __restrict__ W2, v4i* __restrict__ Bf2) {
  int bid  = blockIdx.x;              // d*NKS2 + ks
  int lane = threadIdx.x;
  int ks = bid % NKS2, d = bid / NKS2;
  int o     = lane & 15;
  int kbase = ks * 64 + (lane >> 4) * 16;
  uint32_t wds[4] = {0, 0, 0, 0};
  for (int j = 0; j < 16; ++j) {
    int k = kbase + j;
    int dig = 0;
    if (o < N_O && k < N_H) {
      double w = (double)W2[(size_t)o * N_H + k];
      int r = (int)llround(w * 268435456.0);
      for (int dd = 0; dd <= d; ++dd) {
        dig = (int)(int8_t)(uint8_t)(r & 255);
        r = (r - dig) >> 8;
      }
    }
    wds[j >> 2] |= ((uint32_t)(uint8_t)(int8_t)dig) << (8 * (j & 3));
  }
  v4i v; v[0] = (int)wds[0]; v[1] = (int)wds[1]; v[2] = (int)wds[2]; v[3] = (int)wds[3];
  Bf2[(size_t)bid * 64 + lane] = v;
}

// ---- k_gemm1m: exact int8-digit MFMA; a1 = integer-valued f64 (units 2^-28) ----
__global__ __launch_bounds__(256, 2) void k_gemm1m(const uint32_t* __restrict__ s0w,
                                                   const v4i* __restrict__ Bf,
                                                   double* __restrict__ a1, int rowbase) {
  __shared__ __attribute__((aligned(16))) uint8_t Alds[64 * ASTRIDE];
  int tid = threadIdx.x;
  int mb = blockIdx.x, nb = blockIdx.y;
  const uint32_t* wbase = s0w + (size_t)(rowbase + mb * 64) * NW;
  for (int idx = tid; idx < 64 * NW; idx += 256) {
    int row = idx / NW;
    int w = idx - row * NW;
    uint32_t bits = wbase[idx];
    uint4 q0, q1;
    q0.x = expand4(bits & 0xF);         q0.y = expand4((bits >> 4) & 0xF);
    q0.z = expand4((bits >> 8) & 0xF);  q0.w = expand4((bits >> 12) & 0xF);
    q1.x = expand4((bits >> 16) & 0xF); q1.y = expand4((bits >> 20) & 0xF);
    q1.z = expand4((bits >> 24) & 0xF); q1.w = expand4((bits >> 28) & 0xF);
    uint8_t* dst = &Alds[(size_t)row * ASTRIDE + w * 32];
    *(uint4*)dst = q0;
    *(uint4*)(dst + 16) = q1;
  }
  __syncthreads();
  int wave = tid >> 6, lane = tid & 63;
  int nt = nb * 4 + wave;
  if (nt >= NTILES) return;
  int lrow = lane & 15, quad = lane >> 4;
  const v4i* bb = Bf + (size_t)nt * NKS * 64 + lane;
  const size_t dstr = (size_t)NTILES * NKS * 64;
  v4i acc[4][NDIG];
  #pragma unroll
  for (int mt = 0; mt < 4; ++mt)
    #pragma unroll
    for (int d = 0; d < NDIG; ++d) { acc[mt][d][0]=0; acc[mt][d][1]=0; acc[mt][d][2]=0; acc[mt][d][3]=0; }
  uint32_t abase[4];
  #pragma unroll
  for (int mt = 0; mt < 4; ++mt) abase[mt] = (uint32_t)((mt * 16 + lrow) * ASTRIDE + quad * 16);
  for (int ks = 0; ks < NKS; ++ks) {
    v4i af[4];
    #pragma unroll
    for (int mt = 0; mt < 4; ++mt) af[mt] = *(const v4i*)&Alds[abase[mt] + ks * 64];
    v4i bf[NDIG];
    #pragma unroll
    for (int d = 0; d < NDIG; ++d) bf[d] = bb[(size_t)d * dstr + ks * 64];
    #pragma unroll
    for (int mt = 0; mt < 4; ++mt)
      #pragma unroll
      for (int d = 0; d < NDIG; ++d)
        acc[mt][d] = __builtin_amdgcn_mfma_i32_16x16x64_i8(af[mt], bf[d], acc[mt][d], 0, 0, 0);
  }
  int o = nt * 16 + lrow;               // pad cols o in [410,416) get exact zeros
  #pragma unroll
  for (int mt = 0; mt < 4; ++mt)
    #pragma unroll
    for (int r = 0; r < 4; ++r) {
      int m = mb * 64 + mt * 16 + quad * 4 + r;
      double v = (double)acc[mt][0][r]
               + 256.0      * (double)acc[mt][1][r]
               + 65536.0    * (double)acc[mt][2][r]
               + 16777216.0 * (double)acc[mt][3][r];
      a1[(size_t)m * NHP + o] = v;
    }
}

// ---- k_fir1i: exact truncated-IIR scan for the SRM FIR + threshold -> s1 ----
// eps[k] = c*k*q^k; y[t] = c*(S2[t] - q^64*(S2[t-64] + 64*S1[t-64])), B-scan lags 64.
// grid (4 o-groups of 104, 2 t-segments, nc); block 128 (104 active lanes).
// Per-lane LDS ring holds the 64-deep x history (no cross-lane use, no barriers).
__global__ __launch_bounds__(128) void k_fir1i(const double* __restrict__ a1,
                                               uint8_t* __restrict__ s1) {
  __shared__ double ring[64][104];     // 53248 B -> 3 blocks/CU
  int col = threadIdx.x;
  if (col >= 104) return;
  int o   = blockIdx.x * 104 + col;    // 0..415
  int seg = blockIdx.y;
  int nn  = blockIdx.z;
  const double q   = exp(-0.1);
  const double q64 = exp(-6.4);
  const double cS  = (exp(1.0) / 10.0) * (1.0 / 268435456.0);
  int T0 = seg * 150, T1 = T0 + 150;
  int W = T0 - 63; if (W < 0) W = 0;
  const double* base = a1 + (size_t)nn * TT * NHP + o;
  uint8_t* sbase = s1 + (size_t)nn * TT * SSTR + o;
  double s1a = 0.0, s2a = 0.0, s1b = 0.0, s2b = 0.0;
  // warm-up: feed x[W..T0) into the A-scan and the ring
  #pragma unroll 4
  for (int p = W; p < T0; ++p) {
    double x = base[(size_t)p * NHP];
    ring[p & 63][col] = x;
    s2a = q * (s2a + s1a);
    s1a = q * s1a + x;
  }
  // phase 1: t - W <= 63 -> no taps beyond 63 yet, no tail needed
  int tB = W + 64; if (tB > T1) tB = T1;
  #pragma unroll 4
  for (int t = T0; t < tB; ++t) {
    double x = base[(size_t)t * NHP];
    ring[t & 63][col] = x;
    s2a = q * (s2a + s1a);
    s1a = q * s1a + x;
    sbase[(size_t)t * SSTR] = (cS * s2a >= 10.0) ? 1 : 0;
  }
  // phase 2: subtract the k>=64 tail via the 64-lagged B-scan
  #pragma unroll 4
  for (int t = tB; t < T1; ++t) {
    double xb = ring[t & 63][col];     // = x[t-64]; read BEFORE overwrite
    double xa = base[(size_t)t * NHP];
    ring[t & 63][col] = xa;
    s2b = q * (s2b + s1b);
    s1b = q * s1b + xb;
    s2a = q * (s2a + s1a);
    s1a = q * s1a + xa;
    double y = cS * (s2a - q64 * (s2b + 64.0 * s1b));
    sbase[(size_t)t * SSTR] = (y >= 10.0) ? 1 : 0;
  }
}

// ---- k_gemm2m: layer-2 exact int8-digit MFMA; a2 integer-valued f64 (x 2^28) ----
__global__ void k_gemm2m(const uint8_t* __restrict__ s1, const v4i* __restrict__ Bf2,
                         double* __restrict__ a2) {
  int tid = threadIdx.x;
  int wave = tid >> 6, lane = tid & 63;
  int m0 = (blockIdx.x * 4 + wave) * 16;
  int lrow = lane & 15, quad = lane >> 4;
  v4i acc[NDIG];
  #pragma unroll
  for (int d = 0; d < NDIG; ++d) { acc[d][0]=0; acc[d][1]=0; acc[d][2]=0; acc[d][3]=0; }
  const uint8_t* arow = s1 + (size_t)(m0 + lrow) * SSTR + quad * 16;
  for (int ks = 0; ks < NKS2; ++ks) {
    v4i af = *(const v4i*)(arow + ks * 64);
    #pragma unroll
    for (int d = 0; d < NDIG; ++d) {
      v4i bf = Bf2[(size_t)(d * NKS2 + ks) * 64 + lane];
      acc[d] = __builtin_amdgcn_mfma_i32_16x16x64_i8(af, bf, acc[d], 0, 0, 0);
    }
  }
  int o = lrow;
  if (o < N_O) {
    #pragma unroll
    for (int r = 0; r < 4; ++r) {
      int m = m0 + quad * 4 + r;
      int nn = m / TT;
      int t = m - nn * TT;
      double v = (double)acc[0][r]
               + 256.0      * (double)acc[1][r]
               + 65536.0    * (double)acc[2][r]
               + 16777216.0 * (double)acc[3][r];
      a2[((size_t)nn * N_O + o) * TT + t] = v;
    }
  }
}

// ---- k_fir2: f64 FIR (scaled eps) + threshold -> final spikes ----
__global__ void k_fir2(const double* __restrict__ a2, const double* __restrict__ epsb,
                       float* __restrict__ out, int n0, int nc) {
  int flat = blockIdx.x * 256 + threadIdx.x;
  if (flat >= nc * N_O * TT) return;
  int t    = flat % TT;
  int rest = flat / TT;
  int o    = rest % N_O;
  int nn   = rest / N_O;
  const double* arow = a2 + ((size_t)nn * N_O + o) * TT;
  const double* epsS = epsb + KL;     // scaled eps[k] at 64+k
  double u = 0.0;
  int kmax = (t < KL - 1) ? t : (KL - 1);
  for (int k = 0; k <= kmax; ++k) u += epsS[k] * arow[t - k];
  out[(((size_t)(n0 + nn)) * N_O + o) * TT + t] = (u >= 10.0) ? 1.0f : 0.0f;
}

extern "C" void kernel_launch(void* const* d_in, const int* in_sizes, int n_in,
                              void* d_out, int out_size, void* d_ws, size_t ws_size,
                              hipStream_t stream) {
  const float* img   = (const float*)d_in[0];
  const float* randu = (const float*)d_in[1];
  const float* W1    = (const float*)d_in[2];
  const float* W2    = (const float*)d_in[3];
  float* out = (float*)d_out;

  const size_t fixedB = (((size_t)N_B * TT * NW * 4 + 511) & ~511UL)
                      + (((size_t)NDIG * NTILES * NKS * 64 * 16 + 511) & ~511UL)
                      + (((size_t)NDIG * NKS2 * 64 * 16 + 511) & ~511UL)
                      + ((128 * 8 + 511) & ~511UL);
  const size_t perN = (size_t)TT * NHP * 8 + (size_t)TT * SSTR + (size_t)N_O * TT * 8;
  int nc = 16;
  const int cands[3] = {128, 64, 32};
  for (int ci = 0; ci < 3; ++ci)
    if (fixedB + (size_t)cands[ci] * perN + 8192 <= ws_size) { nc = cands[ci]; break; }
  const int nchunk = N_B / nc;

  char* ws = (char*)d_ws;
  size_t off = 0;
  auto alloc = [&](size_t bytes) -> void* {
    void* p = ws + off;
    off = (off + bytes + 511) & ~(size_t)511;
    return p;
  };
  uint32_t* s0w  = (uint32_t*)alloc((size_t)N_B * TT * NW * sizeof(uint32_t));
  v4i*      Bf   = (v4i*)     alloc((size_t)NDIG * NTILES * NKS * 64 * 16);
  v4i*      Bf2  = (v4i*)     alloc((size_t)NDIG * NKS2 * 64 * 16);
  double*   epsb = (double*)  alloc(128 * sizeof(double));
  double*   a1   = (double*)  alloc((size_t)nc * TT * NHP * sizeof(double));
  uint8_t*  s1   = (uint8_t*) alloc((size_t)nc * TT * SSTR);
  double*   a2   = (double*)  alloc((size_t)nc * N_O * TT * sizeof(double));
  if (off > ws_size) return;

  k_pack  <<<dim3(5, N_B), 64, 0, stream>>>(randu, img, s0w);
  k_eps   <<<dim3(1), 64, 0, stream>>>(epsb);
  k_bprep <<<dim3(NDIG * NTILES * NKS), 64, 0, stream>>>(W1, Bf);
  k_bprep2<<<dim3(NDIG * NKS2), 64, 0, stream>>>(W2, Bf2);

  for (int c = 0; c < nchunk; ++c) {
    int n0 = c * nc;
    k_gemm1m<<<dim3(nc * TT / 64, 7),             256, 0, stream>>>(s0w, Bf, a1, n0 * TT);
    k_fir1i <<<dim3(4, 2, nc),                    128, 0, stream>>>(a1, s1);
    k_gemm2m<<<dim3(nc * TT / 64),                256, 0, stream>>>(s1, Bf2, a2);
    k_fir2  <<<dim3((nc * N_O * TT + 255) / 256), 256, 0, stream>>>(a2, epsb, out, n0, nc);
  }
}